// Round 5
// baseline (129.750 us; speedup 1.0000x reference)
//
#include <hip/hip_runtime.h>
#include <cstdint>

#define D 128
#define K 1024
#define NB 4096
#define BB 8     // rows per block in main kernel
#define TK 64    // centroid rows per LDS tile (fallback path)
#define FEPS 1e-6f

typedef unsigned long long u64;

// ============================================================================
// ws layout (fast path):
//   sval : [D][K] f32   — each column of centroids sorted ascending   (512KB)
//   shead: [D][K] u16   — run-head original index per sorted position (256KB)
//   ssamp: [64][D] f32  — transposed sample table, ssamp[s][d]=sval[d][16s] (32KB)
//   ext  : [0:128) col min val, [128:256) col max val (f32);
//          as ints [256:384) first idx of min, [384:512) first idx of max (2KB)
// ============================================================================

// ---------------------------------------------------------------------------
// Bitonic compare-exchange stages. Element i = j*64 + lane,
// key = (monotone-mapped value <<32) | original index.
// lane_stage_rt: runtime sz/st (st<=32, cross-lane via shfl) — ONE body copy
// (code-size: the fully-unrolled network thrashed the 32KB I$ at 1 wave/CU).
// bstage_reg: compile-time JB (register indexing must be static).
// ---------------------------------------------------------------------------
__device__ __forceinline__ void lane_stage_rt(u64 (&key)[16], int lane, int sz, int st) {
    #pragma unroll
    for (int j = 0; j < 16; ++j) {
        u64 a = key[j];
        u64 b = __shfl_xor(a, st, 64);
        int i = j * 64 + lane;
        bool keepMin = (((lane & st) == 0) == ((i & sz) == 0));
        u64 mn = a < b ? a : b;
        u64 mx = a ^ b ^ mn;
        key[j] = keepMin ? mn : mx;
    }
}
template<int SZ, int JB>   // stride = JB*64: register-pair exchange
__device__ __forceinline__ void bstage_reg(u64 (&key)[16]) {
    #pragma unroll
    for (int j = 0; j < 16; ++j) {
        if ((j & JB) == 0) {
            const int p = j | JB;
            u64 a = key[j], b = key[p];
            bool up = (((j * 64) & SZ) == 0);
            u64 mn = a < b ? a : b;
            u64 mx = a ^ b ^ mn;
            key[j] = up ? mn : mx;
            key[p] = up ? mx : mn;
        }
    }
}

// ---------------------------------------------------------------------------
// Kernel A: per-column sort (value,idx), run heads, samples, extremes.
// One block = one wave = one column. No barriers in the sort network.
// ---------------------------------------------------------------------------
__global__ __launch_bounds__(64) void sort_columns_kernel(
    const float* __restrict__ cen, float* __restrict__ sval,
    unsigned short* __restrict__ shead, float* __restrict__ ssamp,
    float* __restrict__ ext, float* __restrict__ out)
{
    __shared__ u64 key64[K];   // 8 KB, used only for the run-head pass
    const int dcol = blockIdx.x;
    const int lane = threadIdx.x;

    if (dcol == 0 && lane == 0) out[0] = 0.0f;   // replaces memset dispatch

    u64 key[16];
    #pragma unroll
    for (int j = 0; j < 16; ++j) {
        int k = j * 64 + lane;
        float v = cen[k * D + dcol];
        unsigned int u = __float_as_uint(v);
        u = (u & 0x80000000u) ? ~u : (u | 0x80000000u);   // monotone map
        key[j] = ((u64)u << 32) | (unsigned int)k;
    }

    // bitonic network, compact-code driver: sz = 2..1024
    #pragma unroll 1
    for (int szl = 1; szl <= 10; ++szl) {
        const int sz = 1 << szl;
        switch (szl) {   // register stages (strides >= 64), compile-time JB
            case 7:  bstage_reg<128, 1>(key); break;
            case 8:  bstage_reg<256, 2>(key);  bstage_reg<256, 1>(key); break;
            case 9:  bstage_reg<512, 4>(key);  bstage_reg<512, 2>(key);
                     bstage_reg<512, 1>(key); break;
            case 10: bstage_reg<1024, 8>(key); bstage_reg<1024, 4>(key);
                     bstage_reg<1024, 2>(key); bstage_reg<1024, 1>(key); break;
            default: break;
        }
        int st0 = (sz >> 1) > 32 ? 32 : (sz >> 1);
        #pragma unroll 1
        for (int st = st0; st >= 1; st >>= 1)
            lane_stage_rt(key, lane, sz, st);
    }

    #pragma unroll
    for (int j = 0; j < 16; ++j) key64[j * 64 + lane] = key[j];
    __syncthreads();

    #pragma unroll 1
    for (int j = 0; j < 16; ++j) {
        int p = j * 64 + lane;
        u64 kp = key[j];
        unsigned int vb = (unsigned int)(kp >> 32);
        int p0 = p;
        while (p0 > 0 && (unsigned int)(key64[p0 - 1] >> 32) == vb) --p0;  // rare
        int head = (int)(key64[p0] & 1023u);
        unsigned int u = (vb & 0x80000000u) ? (vb & 0x7FFFFFFFu) : ~vb;    // unmap
        float v = __uint_as_float(u);
        sval[dcol * K + p] = v;
        shead[dcol * K + p] = (unsigned short)head;
        if ((p & 15) == 0) ssamp[(p >> 4) * D + dcol] = v;   // transposed
        if (p == 0)     { ext[dcol]     = v; ((int*)ext)[2 * D + dcol] = head; }
        if (p == K - 1) { ext[D + dcol] = v; ((int*)ext)[3 * D + dcol] = head; }
    }
}

// ---------------------------------------------------------------------------
// Main kernel v3: 3-level search (global coarse/fine from L2-resident ssamp ->
// one batched global run), extremes argmax, byte-packed LDS-count mode, loss.
// LDS 20KB (vs 41KB) -> ~5 blocks/CU; 3 barriers (vs 6).
// ---------------------------------------------------------------------------
__global__ __launch_bounds__(256) void cluster_triplet_v3_kernel(
    const float* __restrict__ x, const float* __restrict__ cen,
    const float* __restrict__ sval, const unsigned short* __restrict__ shead,
    const float* __restrict__ ssamp, const float* __restrict__ ext,
    float* __restrict__ out)
{
    __shared__ float xs[BB * D];                // 4 KB
    __shared__ unsigned int cntA[BB * K / 4];   // 8 KB, byte-packed counts (idx_min)
    __shared__ unsigned int cntB[BB * K / 4];   // 8 KB, byte-packed counts (idx_max)
    __shared__ int modes[2 * BB];

    const int t = threadIdx.x;
    const int b0 = blockIdx.x * BB;

    ((float4*)xs)[t] = ((const float4*)(x + (size_t)b0 * D))[t];
    {   // zero both count buffers: 1024 uint4 / 256 threads = 4 each
        uint4 z = make_uint4(0u, 0u, 0u, 0u);
        uint4* a4 = (uint4*)cntA;
        uint4* b4 = (uint4*)cntB;
        #pragma unroll
        for (int j = 0; j < 2; ++j) { a4[t + 256 * j] = z; b4[t + 256 * j] = z; }
    }
    __syncthreads();

    const int d = t & (D - 1);
    const int g = t >> 7;

    float xr[4];
    #pragma unroll
    for (int r = 0; r < 4; ++r) xr[r] = xs[(g * 4 + r) * D + d];

    // level 0: 8 coarse samples, coalesced global (L2-resident, 32KB table)
    float c8[8];
    #pragma unroll
    for (int m = 0; m < 8; ++m) c8[m] = ssamp[(m * 8) * D + d];

    // level 1: per chain, 8 fine samples -> ss = last s in [0,64) with samp[s]<=x
    int ss[4];
    #pragma unroll
    for (int r = 0; r < 4; ++r) {
        int cnt8 = 0;
        #pragma unroll
        for (int m = 0; m < 8; ++m) cnt8 += (c8[m] <= xr[r]) ? 1 : 0;
        int cb = cnt8 > 0 ? cnt8 - 1 : 0;
        int cf = 0;
        #pragma unroll
        for (int i = 1; i < 8; ++i) cf += (ssamp[(cb * 8 + i) * D + d] <= xr[r]) ? 1 : 0;
        ss[r] = (cnt8 == 0) ? -1 : cb * 8 + cf;
    }

    // level 2: one batched global load per chain (16 vals + 16 heads + 1 extra)
    int q0[4];
    float4 v4[4][4];
    uint4  h4[4][2];
    unsigned int he[4];
    #pragma unroll
    for (int r = 0; r < 4; ++r) {
        q0[r] = (ss[r] < 0 ? 0 : ss[r]) * 16;
        const int base = d * K + q0[r];
        const float4* vp = (const float4*)(sval + base);
        v4[r][0] = vp[0]; v4[r][1] = vp[1]; v4[r][2] = vp[2]; v4[r][3] = vp[3];
        const uint4* hp = (const uint4*)(shead + base);
        h4[r][0] = hp[0]; h4[r][1] = hp[1];
        int qe = q0[r] + 16; if (qe > K - 1) qe = K - 1;
        he[r] = shead[d * K + qe];
    }

    #pragma unroll
    for (int r = 0; r < 4; ++r) {
        const float xv = xr[r];
        float vals[16];
        vals[0]=v4[r][0].x; vals[1]=v4[r][0].y; vals[2]=v4[r][0].z; vals[3]=v4[r][0].w;
        vals[4]=v4[r][1].x; vals[5]=v4[r][1].y; vals[6]=v4[r][1].z; vals[7]=v4[r][1].w;
        vals[8]=v4[r][2].x; vals[9]=v4[r][2].y; vals[10]=v4[r][2].z; vals[11]=v4[r][2].w;
        vals[12]=v4[r][3].x; vals[13]=v4[r][3].y; vals[14]=v4[r][3].z; vals[15]=v4[r][3].w;
        unsigned int hu[8];
        hu[0]=h4[r][0].x; hu[1]=h4[r][0].y; hu[2]=h4[r][0].z; hu[3]=h4[r][0].w;
        hu[4]=h4[r][1].x; hu[5]=h4[r][1].y; hu[6]=h4[r][1].z; hu[7]=h4[r][1].w;
        int hds[16];
        #pragma unroll
        for (int i = 0; i < 16; ++i) hds[i] = (int)((hu[i >> 1] >> ((i & 1) * 16)) & 0xFFFFu);

        float v1 = 0.f, v2 = 0.f; int h1 = 0, h2 = 0; bool has1 = false, has2 = false;
        #pragma unroll
        for (int i = 0; i < 16; ++i) {          // last val <= x (ascending)
            bool c = vals[i] <= xv;
            v1 = c ? vals[i] : v1; h1 = c ? hds[i] : h1; has1 = has1 || c;
        }
        #pragma unroll
        for (int i = 15; i >= 0; --i) {         // first val > x
            bool c = vals[i] > xv;
            v2 = c ? vals[i] : v2; h2 = c ? hds[i] : h2; has2 = has2 || c;
        }
        if (!has2) {                             // ran off the 16-run
            v2 = (ss[r] < 63) ? ssamp[(ss[r] + 1) * D + d] : 0.f;
            h2 = (int)he[r];
            has2 = (ss[r] < 63);
        }
        float d1 = xv - v1, d2 = xv - v2;
        float s1 = has1 ? d1 * d1 : 3.4e38f;
        float s2 = has2 ? d2 * d2 : 3.4e38f;
        int idx;
        if (s1 < s2) idx = h1;
        else if (s2 < s1) idx = h2;
        else idx = h1 < h2 ? h1 : h2;            // sq tie -> smaller original index

        const int rr = g * 4 + r;                // direct count-atomic, no staging
        atomicAdd(&cntA[(rr << 8) + (idx >> 2)], 1u << ((idx & 3) * 8));
    }

    // idx_max from column extremes (reference rounding), direct count-atomic
    {
        float cminv = ext[d], cmaxv = ext[D + d];
        int cmini = ((const int*)ext)[2 * D + d];
        int cmaxi = ((const int*)ext)[3 * D + d];
        #pragma unroll
        for (int r = 0; r < 4; ++r) {
            float d1 = xr[r] - cminv;
            float d2 = xr[r] - cmaxv;
            float s1 = d1 * d1, s2 = d2 * d2;
            int idx;
            if (s1 > s2) idx = cmini;
            else if (s2 > s1) idx = cmaxi;
            else idx = (cmini < cmaxi) ? cmini : cmaxi;
            const int rr = g * 4 + r;
            atomicAdd(&cntB[(rr << 8) + (idx >> 2)], 1u << ((idx & 3) * 8));
        }
    }
    __syncthreads();

    // mode scan: 32 lanes per row, 8 packed words each, both buffers at once
    const int row = t >> 5;
    const int lane = t & 31;
    {
        unsigned int bkeyA = 0u, bkeyB = 0u;
        #pragma unroll
        for (int j = 0; j < 8; ++j) {
            const int w = j * 32 + lane;
            unsigned int wA = cntA[(row << 8) + w];
            unsigned int wB = cntB[(row << 8) + w];
            #pragma unroll
            for (int sub = 0; sub < 4; ++sub) {
                const unsigned int idx = (unsigned)(w * 4 + sub);
                unsigned int cA = (wA >> (sub * 8)) & 0xFFu;
                unsigned int cB = (wB >> (sub * 8)) & 0xFFu;
                unsigned int kA = (cA << 10) | (1023u - idx);
                unsigned int kB = (cB << 10) | (1023u - idx);
                bkeyA = kA > bkeyA ? kA : bkeyA;
                bkeyB = kB > bkeyB ? kB : bkeyB;
            }
        }
        #pragma unroll
        for (int m = 16; m >= 1; m >>= 1) {
            unsigned int oA = __shfl_xor(bkeyA, m);
            unsigned int oB = __shfl_xor(bkeyB, m);
            bkeyA = oA > bkeyA ? oA : bkeyA;
            bkeyB = oB > bkeyB ? oB : bkeyB;
        }
        if (lane == 0) {
            modes[row]      = 1023 - (int)(bkeyA & 1023u);
            modes[BB + row] = 1023 - (int)(bkeyB & 1023u);
        }
    }
    __syncthreads();

    // triplet distances: 32 lanes per row, 4 dims each
    {
        int pm = modes[row];
        int nm = modes[BB + row];
        const float* pr = cen + (size_t)pm * D;
        const float* nr = cen + (size_t)nm * D;
        float a1 = 0.f, a2 = 0.f, a3 = 0.f;
        #pragma unroll
        for (int j = 0; j < 4; ++j) {
            int dd = j * 32 + lane;
            float xv = xs[row * D + dd];
            float pv = pr[dd], nv = nr[dd];
            float e1 = xv - pv + FEPS;
            float e2 = xv - nv + FEPS;
            float e3 = pv - nv + FEPS;
            a1 += e1 * e1; a2 += e2 * e2; a3 += e3 * e3;
        }
        #pragma unroll
        for (int m = 16; m >= 1; m >>= 1) {
            a1 += __shfl_xor(a1, m);
            a2 += __shfl_xor(a2, m);
            a3 += __shfl_xor(a3, m);
        }
        if (lane == 0) {
            float dp = sqrtf(a1);
            float dneg = fminf(sqrtf(a2), sqrtf(a3));
            float term = dp - dneg + 1.0f;
            if (term > 0.f) atomicAdd(out, term * (1.0f / NB));
        }
    }
}

// ===========================================================================
// Fallback path (verified round-1 kernels) for small ws_size
// ===========================================================================
__global__ __launch_bounds__(256) void col_extremes_kernel(
    const float* __restrict__ cen, float* __restrict__ ws)
{
    __shared__ float mv[256]; __shared__ int mi[256];
    __shared__ float Mv[256]; __shared__ int Mi[256];
    const int dcol = blockIdx.x;
    const int t = threadIdx.x;

    float lminv = 3.4e38f; int lmini = 0;
    float lmaxv = -3.4e38f; int lmaxi = 0;
    #pragma unroll
    for (int j = 0; j < 4; ++j) {
        int k = t * 4 + j;
        float v = cen[k * D + dcol];
        if (v < lminv) { lminv = v; lmini = k; }
        if (v > lmaxv) { lmaxv = v; lmaxi = k; }
    }
    mv[t] = lminv; mi[t] = lmini; Mv[t] = lmaxv; Mi[t] = lmaxi;
    __syncthreads();
    for (int s = 128; s > 0; s >>= 1) {
        if (t < s) {
            float ov = mv[t + s]; int oi = mi[t + s];
            if (ov < mv[t] || (ov == mv[t] && oi < mi[t])) { mv[t] = ov; mi[t] = oi; }
            float Ov = Mv[t + s]; int Oi = Mi[t + s];
            if (Ov > Mv[t] || (Ov == Mv[t] && Oi < Mi[t])) { Mv[t] = Ov; Mi[t] = Oi; }
        }
        __syncthreads();
    }
    if (t == 0) {
        ws[dcol]     = mv[0];
        ws[D + dcol] = Mv[0];
        ((int*)ws)[2 * D + dcol] = mi[0];
        ((int*)ws)[3 * D + dcol] = Mi[0];
    }
}

__global__ __launch_bounds__(256) void cluster_triplet_kernel(
    const float* __restrict__ x, const float* __restrict__ cen,
    const float* __restrict__ ws, float* __restrict__ out)
{
    __shared__ float ctile[TK * D];
    __shared__ float xs[BB * D];
    __shared__ unsigned short imin[BB * D];
    __shared__ unsigned short imax[BB * D];
    __shared__ int modes[2 * BB];

    const int t = threadIdx.x;
    const int b0 = blockIdx.x * BB;

    ((float4*)xs)[t] = ((const float4*)(x + (size_t)b0 * D))[t];
    __syncthreads();

    const int d = t & (D - 1);
    const int g = t >> 7;

    float xr[4];
    #pragma unroll
    for (int r = 0; r < 4; ++r) xr[r] = xs[(g * 4 + r) * D + d];

    float best[4]; int bidx[4];
    #pragma unroll
    for (int r = 0; r < 4; ++r) { best[r] = 3.4e38f; bidx[r] = 0; }

    for (int kt = 0; kt < K / TK; ++kt) {
        __syncthreads();
        {
            const float4* src = (const float4*)(cen + (size_t)kt * TK * D);
            float4* dst = (float4*)ctile;
            #pragma unroll
            for (int j = 0; j < 8; ++j) dst[t + 256 * j] = src[t + 256 * j];
        }
        __syncthreads();
        #pragma unroll 8
        for (int kk = 0; kk < TK; ++kk) {
            float cv = ctile[kk * D + d];
            int kg = kt * TK + kk;
            #pragma unroll
            for (int r = 0; r < 4; ++r) {
                float ad = fabsf(xr[r] - cv);
                if (ad < best[r]) { best[r] = ad; bidx[r] = kg; }
            }
        }
    }

    #pragma unroll
    for (int r = 0; r < 4; ++r) imin[(g * 4 + r) * D + d] = (unsigned short)bidx[r];

    {
        float cminv = ws[d], cmaxv = ws[D + d];
        int cmini = ((const int*)ws)[2 * D + d];
        int cmaxi = ((const int*)ws)[3 * D + d];
        #pragma unroll
        for (int r = 0; r < 4; ++r) {
            float d1 = xr[r] - cminv;
            float d2 = xr[r] - cmaxv;
            float s1 = d1 * d1, s2 = d2 * d2;
            int idx;
            if (s1 > s2) idx = cmini;
            else if (s2 > s1) idx = cmaxi;
            else idx = (cmini < cmaxi) ? cmini : cmaxi;
            imax[(g * 4 + r) * D + d] = (unsigned short)idx;
        }
    }
    __syncthreads();

    unsigned int* counts = (unsigned int*)ctile;
    const int row = t >> 5;
    const int lane = t & 31;
    for (int pass = 0; pass < 2; ++pass) {
        {
            uint4* cz = (uint4*)counts;
            uint4 z = make_uint4(0u, 0u, 0u, 0u);
            #pragma unroll
            for (int j = 0; j < 8; ++j) cz[t + 256 * j] = z;
        }
        __syncthreads();
        const unsigned short* src = (pass == 0) ? imin : imax;
        #pragma unroll
        for (int r = 0; r < 4; ++r) {
            int rr = g * 4 + r;
            atomicAdd(&counts[rr * K + (int)src[rr * D + d]], 1u);
        }
        __syncthreads();
        unsigned int bkey = 0u;
        for (int j = 0; j < 32; ++j) {
            int idx = j * 32 + lane;
            unsigned int cnt = counts[row * K + idx];
            unsigned int key = (cnt << 10) | (1023u - (unsigned)idx);
            bkey = (key > bkey) ? key : bkey;
        }
        #pragma unroll
        for (int m = 16; m >= 1; m >>= 1) {
            unsigned int o = __shfl_xor(bkey, m);
            bkey = (o > bkey) ? o : bkey;
        }
        if (lane == 0) modes[pass * BB + row] = 1023 - (int)(bkey & 1023u);
        __syncthreads();
    }

    {
        int pm = modes[0 * BB + row];
        int nm = modes[1 * BB + row];
        const float* pr = cen + (size_t)pm * D;
        const float* nr = cen + (size_t)nm * D;
        float a1 = 0.f, a2 = 0.f, a3 = 0.f;
        #pragma unroll
        for (int j = 0; j < 4; ++j) {
            int dd = j * 32 + lane;
            float xv = xs[row * D + dd];
            float pv = pr[dd], nv = nr[dd];
            float e1 = xv - pv + FEPS;
            float e2 = xv - nv + FEPS;
            float e3 = pv - nv + FEPS;
            a1 += e1 * e1; a2 += e2 * e2; a3 += e3 * e3;
        }
        #pragma unroll
        for (int m = 16; m >= 1; m >>= 1) {
            a1 += __shfl_xor(a1, m);
            a2 += __shfl_xor(a2, m);
            a3 += __shfl_xor(a3, m);
        }
        if (lane == 0) {
            float dp = sqrtf(a1);
            float dneg = fminf(sqrtf(a2), sqrtf(a3));
            float term = dp - dneg + 1.0f;
            if (term > 0.f) atomicAdd(out, term * (1.0f / NB));
        }
    }
}

extern "C" void kernel_launch(void* const* d_in, const int* in_sizes, int n_in,
                              void* d_out, int out_size, void* d_ws, size_t ws_size,
                              hipStream_t stream) {
    (void)in_sizes; (void)n_in; (void)out_size;
    const float* x   = (const float*)d_in[0];   // [4096,128] f32
    const float* cen = (const float*)d_in[1];   // [1024,128] f32
    float* out = (float*)d_out;                 // scalar f32

    const size_t need = (size_t)D * K * 4 + (size_t)D * K * 2
                      + (size_t)64 * D * 4 + (size_t)4 * D * 4;
    if (ws_size >= need) {
        float* sval = (float*)d_ws;                                 // 512 KB
        unsigned short* shead = (unsigned short*)(sval + D * K);    // 256 KB
        float* ssamp = (float*)(shead + D * K);                     // 32 KB
        float* ext = ssamp + 64 * D;                                // 2 KB
        sort_columns_kernel<<<D, 64, 0, stream>>>(cen, sval, shead, ssamp, ext, out);
        cluster_triplet_v3_kernel<<<NB / BB, 256, 0, stream>>>(x, cen, sval, shead, ssamp, ext, out);
    } else {
        float* ws = (float*)d_ws;
        hipMemsetAsync(d_out, 0, sizeof(float), stream);
        col_extremes_kernel<<<D, 256, 0, stream>>>(cen, ws);
        cluster_triplet_kernel<<<NB / BB, 256, 0, stream>>>(x, cen, ws, out);
    }
}